// Round 2
// baseline (110.928 us; speedup 1.0000x reference)
//
#include <hip/hip_runtime.h>

#define BB 4
#define NN 2048
#define DD 256
#define TILE_N 32                 // n per block
#define NPW 8                     // n per wave (4 waves * 8 = 32)
#define NT (NN / TILE_N)          // 64 n-tiles
#define MLEN NN                   // full m-range per block
#define MCH (MLEN / 128)          // 16 chunks of 128 m (2 points/lane)
#define WQ_CAP 128                // per-wave hit queue (lambda ~10.8)
#define NBLK (BB * BB * NT)       // 1024 blocks = exactly 4/CU, co-resident

// Poison-proof record tags: a constant fill pattern P can never satisfy
// P == KEY1^bid AND P == KEY2^bid (KEY1 != KEY2), so the reducer cannot
// mistake re-poisoned workspace for a valid partial.
#define KEY1 0xA5C3E7D1u
#define KEY2 0x3B9ACA07u

// Single fused kernel: block = (pair, n-tile of 32) scanning ALL 2048 m.
// Partials go to tag-validated 16B records (agent-scope release stores,
// cross-XCD visible); block 0 acquires all 1024 records after its own scan
// and writes the final scalar. Eliminates the finalize dispatch + gap.
// d2 math is bit-identical to the verified round-1 kernel (absmax 0.0).
__global__ __launch_bounds__(256, 4) void scan_kernel(const float* __restrict__ feat,
                                                      const float* __restrict__ pts_src,
                                                      const float* __restrict__ pts_dst,
                                                      const int* __restrict__ hptr,
                                                      const int* __restrict__ wptr,
                                                      unsigned int* __restrict__ recs,
                                                      float* __restrict__ out) {
    __shared__ unsigned int wq[4][WQ_CAP];               // per-wave hit queues
    __shared__ unsigned int wqc[4];
    __shared__ float bsum[4];
    __shared__ unsigned int bcnt[4];
    __shared__ float rsum[4], rcnt[4];                   // reducer cross-wave

    const int xcd  = blockIdx.x & 7;                     // dispatch round-robin -> XCD id
    const int slot = blockIdx.x >> 3;                    // 0..127 within XCD
    const int pair = xcd | ((slot >> 6) << 3);           // 2 pairs/XCD share src batch j
    const int tile = slot & 63;
    const int i = pair >> 2;
    const int j = pair & 3;
    const float sx = ((float)(*wptr) - 1.0f) * 0.5f;
    const float sy = ((float)(*hptr) - 1.0f) * 0.5f;

    const int wave = threadIdx.x >> 6;
    const int lane = threadIdx.x & 63;
    if (lane == 0) wqc[wave] = 0u;                       // same-wave order: no barrier

    const int nbase = tile * TILE_N + wave * NPW;
    float psx[NPW], psy[NPW];
#pragma unroll
    for (int k = 0; k < NPW; ++k) {
        psx[k] = fmaf(pts_src[(size_t)(i * NN + nbase + k) * 2 + 0], sx, sx);
        psy[k] = fmaf(pts_src[(size_t)(i * NN + nbase + k) * 2 + 1], sy, sy);
    }

    // lane's view of this pair's full m-range: float4 = 2 raw points
    const float4* pd = (const float4*)(pts_dst + (size_t)pair * NN * 2);

    float4 q = pd[lane];                                 // prefetch chunk 0
#pragma unroll 4
    for (int c = 0; c < MCH; ++c) {
        float4 qn;
        if (c + 1 < MCH) qn = pd[(c + 1) * 64 + lane];   // prefetch next
        const float qx0 = fmaf(q.x, sx, sx), qy0 = fmaf(q.y, sy, sy);
        const float qx1 = fmaf(q.z, sx, sx), qy1 = fmaf(q.w, sy, sy);
        float mn = 1e30f;
#pragma unroll
        for (int k = 0; k < NPW; ++k) {                  // d0/d1 transient (low VGPR)
            const float ax = psx[k] - qx0, ay = psy[k] - qy0;
            const float bx = psx[k] - qx1, by = psy[k] - qy1;
            mn = fminf(mn, fminf(fmaf(ax, ax, ay * ay), fmaf(bx, bx, by * by)));
        }
        if (__ballot(mn <= 64.0f)) {                     // rare slow path: recompute
            const unsigned int m2 = (unsigned int)(c * 128 + 2 * lane);
#pragma unroll
            for (int k = 0; k < NPW; ++k) {
                const float ax = psx[k] - qx0, ay = psy[k] - qy0;
                const float bx = psx[k] - qx1, by = psy[k] - qy1;
                const float d0 = fmaf(ax, ax, ay * ay);
                const float d1 = fmaf(bx, bx, by * by);
                if (fminf(d0, d1) <= 64.0f) {            // per-k early-out
                    if (d0 <= 64.0f) {
                        const unsigned int s2 = atomicAdd(&wqc[wave], 1u);
                        if (s2 < WQ_CAP) wq[wave][s2] = ((unsigned int)k << 11) | m2;
                    }
                    if (d1 <= 64.0f) {
                        const unsigned int s2 = atomicAdd(&wqc[wave], 1u);
                        if (s2 < WQ_CAP) wq[wave][s2] = ((unsigned int)k << 11) | (m2 + 1u);
                    }
                }
            }
        }
        q = qn;
    }

    // ---- tail: 8 hits at a time, 8 lanes/hit; dot + both norms fused ----
    const unsigned int hc = min(wqc[wave], (unsigned int)WQ_CAP);
    const int g = lane >> 3, sub = lane & 7;
    float lsum = 0.0f;
    for (unsigned int h0 = 0; h0 < hc; h0 += 8) {
        const unsigned int hid = h0 + (unsigned int)g;
        const bool valid = hid < hc;
        float dd = 0.0f, aa = 0.0f, bb = 0.0f;
        if (valid) {
            const unsigned int rec = wq[wave][hid];
            const int m = (int)(rec & 2047u);
            const int n = nbase + (int)(rec >> 11);
            const float4* pa = (const float4*)(feat + (size_t)(j * NN + n) * DD);
            const float4* pb = (const float4*)(feat + (size_t)(i * NN + m) * DD);
#pragma unroll
            for (int t = 0; t < 8; ++t) {
                const float4 a = pa[t * 8 + sub];
                const float4 b = pb[t * 8 + sub];
                dd = fmaf(a.x, b.x, fmaf(a.y, b.y, fmaf(a.z, b.z, fmaf(a.w, b.w, dd))));
                aa = fmaf(a.x, a.x, fmaf(a.y, a.y, fmaf(a.z, a.z, fmaf(a.w, a.w, aa))));
                bb = fmaf(b.x, b.x, fmaf(b.y, b.y, fmaf(b.z, b.z, fmaf(b.w, b.w, bb))));
            }
        }
        dd += __shfl_xor(dd, 1, 64);  aa += __shfl_xor(aa, 1, 64);  bb += __shfl_xor(bb, 1, 64);
        dd += __shfl_xor(dd, 2, 64);  aa += __shfl_xor(aa, 2, 64);  bb += __shfl_xor(bb, 2, 64);
        dd += __shfl_xor(dd, 4, 64);  aa += __shfl_xor(aa, 4, 64);  bb += __shfl_xor(bb, 4, 64);
        if (valid && sub == 0) {
            const float p = aa * bb;                     // (|fa|*|fb|)^2 >> eps^2
            float r = rsqrtf(p);
            r = r * (1.5f - 0.5f * p * r * r);           // one Newton step
            lsum += 1.0f - dd * r;
        }
    }
#pragma unroll
    for (int off = 32; off >= 1; off >>= 1) lsum += __shfl_xor(lsum, off, 64);

    // ---- block reduction -> tag-validated record (init-free protocol) ----
    if (lane == 0) { bsum[wave] = lsum; bcnt[wave] = hc; }
    __syncthreads();
    if (threadIdx.x == 0) {
        const float S = bsum[0] + bsum[1] + bsum[2] + bsum[3];
        const unsigned int C = bcnt[0] + bcnt[1] + bcnt[2] + bcnt[3];
        unsigned int* rec = recs + 4u * blockIdx.x;
        __hip_atomic_store(rec + 0, __float_as_uint(S), __ATOMIC_RELAXED, __HIP_MEMORY_SCOPE_AGENT);
        __hip_atomic_store(rec + 1, C,                  __ATOMIC_RELAXED, __HIP_MEMORY_SCOPE_AGENT);
        __hip_atomic_store(rec + 2, KEY1 ^ blockIdx.x,  __ATOMIC_RELEASE, __HIP_MEMORY_SCOPE_AGENT);
        __hip_atomic_store(rec + 3, KEY2 ^ blockIdx.x,  __ATOMIC_RELEASE, __HIP_MEMORY_SCOPE_AGENT);
    }
    if (blockIdx.x != 0) return;

    // ---- block 0: poll all records (acquire), reduce, write scalar ----
    float s = 0.0f, c = 0.0f;
    for (int t = threadIdx.x; t < NBLK; t += 256) {
        unsigned int* rec = recs + 4u * (unsigned int)t;
        const unsigned int e1 = KEY1 ^ (unsigned int)t;
        const unsigned int e2 = KEY2 ^ (unsigned int)t;
        while (__hip_atomic_load(rec + 2, __ATOMIC_ACQUIRE, __HIP_MEMORY_SCOPE_AGENT) != e1 ||
               __hip_atomic_load(rec + 3, __ATOMIC_ACQUIRE, __HIP_MEMORY_SCOPE_AGENT) != e2) {
            __builtin_amdgcn_s_sleep(8);                 // throttle the spin
        }
        s += __uint_as_float(__hip_atomic_load(rec + 0, __ATOMIC_RELAXED, __HIP_MEMORY_SCOPE_AGENT));
        c += (float)__hip_atomic_load(rec + 1, __ATOMIC_RELAXED, __HIP_MEMORY_SCOPE_AGENT);
    }
#pragma unroll
    for (int off = 32; off >= 1; off >>= 1) {
        s += __shfl_xor(s, off, 64);
        c += __shfl_xor(c, off, 64);
    }
    __syncthreads();                                     // bsum/bcnt reuse is done
    if (lane == 0) { rsum[wave] = s; rcnt[wave] = c; }
    __syncthreads();
    if (threadIdx.x == 0) {
        const float S = rsum[0] + rsum[1] + rsum[2] + rsum[3];
        const float C = rcnt[0] + rcnt[1] + rcnt[2] + rcnt[3];
        out[0] = S / fmaxf(C, 1.0f);                     // max(cnt, 1)
    }
}

extern "C" void kernel_launch(void* const* d_in, const int* in_sizes, int n_in,
                              void* d_out, int out_size, void* d_ws, size_t ws_size,
                              hipStream_t stream) {
    const float* feat    = (const float*)d_in[0];   // [B,N,D] f32
    const float* pts_src = (const float*)d_in[1];   // [B,N,2] f32
    const float* pts_dst = (const float*)d_in[2];   // [B,B,N,2] f32
    // d_in[3] = invis_idx — unused by the reference
    const int* hptr = (const int*)d_in[4];          // height (scalar)
    const int* wptr = (const int*)d_in[5];          // width  (scalar)
    float* out = (float*)d_out;

    unsigned int* recs = (unsigned int*)d_ws;       // 1024 x 16 B = 16 KB

    scan_kernel<<<NBLK, 256, 0, stream>>>(feat, pts_src, pts_dst,
                                          hptr, wptr, recs, out);
}

// Round 3
// 87.410 us; speedup vs baseline: 1.2690x; 1.2690x over previous
//
#include <hip/hip_runtime.h>

#define BB 4
#define NN 2048
#define DD 256
#define TILE_N 32                 // n per block
#define NPW 8                     // n per wave (4 waves * 8 = 32)
#define NT (NN / TILE_N)          // 64 n-tiles
#define MSPLIT 2                  // m-range halves
#define MLEN (NN / MSPLIT)        // 1024 m per block
#define MCH (MLEN / 128)          // 8 chunks of 128 m (2 points/lane)
#define WQ_CAP 96                 // per-wave hit queue (lambda ~5.4, round-0 verified)
#define NBLK (BB * BB * NT * MSPLIT)   // 2048 blocks

// Scan kernel, latency-tolerant version:
//  * dst points are staged ONCE per block into LDS (denormed) -> the 8-chunk
//    inner loop reads ds_read_b128 (~120cy, hidden) instead of global loads.
//  * __launch_bounds__(256, 8): VGPR cap 64 -> 8 waves/SIMD (32 waves/CU),
//    2x the latency hiding of the previous VGPR=128 build.
// d2 math bit-identical to the verified kernels: denorm = fmaf(raw, s, s),
// distances as squared differences, threshold 64.0f.
__global__ __launch_bounds__(256, 8) void scan_kernel(const float* __restrict__ feat,
                                                      const float* __restrict__ pts_src,
                                                      const float* __restrict__ pts_dst,
                                                      const int* __restrict__ hptr,
                                                      const int* __restrict__ wptr,
                                                      float* __restrict__ psum,
                                                      unsigned int* __restrict__ pcnt) {
    __shared__ float4 dpts[MLEN / 2];                    // 512 x 16B = 8 KB denormed pts
    __shared__ unsigned int wq[4][WQ_CAP];               // per-wave hit queues
    __shared__ unsigned int wqc[4];
    __shared__ float bsum[4];
    __shared__ unsigned int bcnt[4];

    const int xcd   = blockIdx.x & 7;                    // round-robin -> XCD id
    const int slot  = blockIdx.x >> 3;                   // 0..255 within XCD
    const int pair  = xcd | ((slot >> 7) << 3);          // 2 pairs/XCD share src batch j
    const int tile  = (slot >> 1) & 63;
    const int mhalf = slot & 1;
    const int mbase = mhalf * MLEN;
    const int i = pair >> 2;
    const int j = pair & 3;
    const float sx = ((float)(*wptr) - 1.0f) * 0.5f;
    const float sy = ((float)(*hptr) - 1.0f) * 0.5f;

    const int wave = threadIdx.x >> 6;
    const int lane = threadIdx.x & 63;
    if (lane == 0) wqc[wave] = 0u;                       // same-wave order: no barrier

    // ---- stage this block's m-half into LDS, denormed (same fmaf form) ----
    {
        const float4* pdg = (const float4*)(pts_dst + (size_t)pair * NN * 2 + (size_t)mbase * 2);
        for (int t = threadIdx.x; t < MLEN / 2; t += 256) {
            const float4 r = pdg[t];                     // 2 raw points
            float4 d;
            d.x = fmaf(r.x, sx, sx);  d.y = fmaf(r.y, sy, sy);
            d.z = fmaf(r.z, sx, sx);  d.w = fmaf(r.w, sy, sy);
            dpts[t] = d;
        }
    }

    const int nbase = tile * TILE_N + wave * NPW;
    float psx[NPW], psy[NPW];
#pragma unroll
    for (int k = 0; k < NPW; ++k) {
        psx[k] = fmaf(pts_src[(size_t)(i * NN + nbase + k) * 2 + 0], sx, sx);
        psy[k] = fmaf(pts_src[(size_t)(i * NN + nbase + k) * 2 + 1], sy, sy);
    }
    __syncthreads();                                     // stage visible to all waves

#pragma unroll 2
    for (int c = 0; c < MCH; ++c) {
        const float4 q = dpts[c * 64 + lane];            // ds_read_b128, denormed
        float mn = 1e30f;
#pragma unroll
        for (int k = 0; k < NPW; ++k) {                  // d0/d1 transient (low VGPR)
            const float ax = psx[k] - q.x, ay = psy[k] - q.y;
            const float bx = psx[k] - q.z, by = psy[k] - q.w;
            mn = fminf(mn, fminf(fmaf(ax, ax, ay * ay), fmaf(bx, bx, by * by)));
        }
        if (__ballot(mn <= 64.0f)) {                     // rare slow path: recompute
            const unsigned int m2 = (unsigned int)(mbase + c * 128 + 2 * lane);
#pragma unroll
            for (int k = 0; k < NPW; ++k) {
                const float ax = psx[k] - q.x, ay = psy[k] - q.y;
                const float bx = psx[k] - q.z, by = psy[k] - q.w;
                const float d0 = fmaf(ax, ax, ay * ay);
                const float d1 = fmaf(bx, bx, by * by);
                if (fminf(d0, d1) <= 64.0f) {            // per-k early-out
                    if (d0 <= 64.0f) {
                        const unsigned int s2 = atomicAdd(&wqc[wave], 1u);
                        if (s2 < WQ_CAP) wq[wave][s2] = ((unsigned int)k << 11) | m2;
                    }
                    if (d1 <= 64.0f) {
                        const unsigned int s2 = atomicAdd(&wqc[wave], 1u);
                        if (s2 < WQ_CAP) wq[wave][s2] = ((unsigned int)k << 11) | (m2 + 1u);
                    }
                }
            }
        }
    }

    // ---- tail: 8 hits at a time, 8 lanes/hit; dot + both norms fused ----
    const unsigned int hc = min(wqc[wave], (unsigned int)WQ_CAP);
    const int g = lane >> 3, sub = lane & 7;
    float lsum = 0.0f;
    for (unsigned int h0 = 0; h0 < hc; h0 += 8) {
        const unsigned int hid = h0 + (unsigned int)g;
        const bool valid = hid < hc;
        float dd = 0.0f, aa = 0.0f, bb = 0.0f;
        if (valid) {
            const unsigned int rec = wq[wave][hid];
            const int m = (int)(rec & 2047u);
            const int n = nbase + (int)(rec >> 11);
            const float4* pa = (const float4*)(feat + (size_t)(j * NN + n) * DD);
            const float4* pb = (const float4*)(feat + (size_t)(i * NN + m) * DD);
#pragma unroll
            for (int t = 0; t < 8; ++t) {
                const float4 a = pa[t * 8 + sub];
                const float4 b = pb[t * 8 + sub];
                dd = fmaf(a.x, b.x, fmaf(a.y, b.y, fmaf(a.z, b.z, fmaf(a.w, b.w, dd))));
                aa = fmaf(a.x, a.x, fmaf(a.y, a.y, fmaf(a.z, a.z, fmaf(a.w, a.w, aa))));
                bb = fmaf(b.x, b.x, fmaf(b.y, b.y, fmaf(b.z, b.z, fmaf(b.w, b.w, bb))));
            }
        }
        dd += __shfl_xor(dd, 1, 64);  aa += __shfl_xor(aa, 1, 64);  bb += __shfl_xor(bb, 1, 64);
        dd += __shfl_xor(dd, 2, 64);  aa += __shfl_xor(aa, 2, 64);  bb += __shfl_xor(bb, 2, 64);
        dd += __shfl_xor(dd, 4, 64);  aa += __shfl_xor(aa, 4, 64);  bb += __shfl_xor(bb, 4, 64);
        if (valid && sub == 0) {
            const float p = aa * bb;                     // (|fa|*|fb|)^2 >> eps^2
            float r = rsqrtf(p);
            r = r * (1.5f - 0.5f * p * r * r);           // one Newton step
            lsum += 1.0f - dd * r;
        }
    }
#pragma unroll
    for (int off = 32; off >= 1; off >>= 1) lsum += __shfl_xor(lsum, off, 64);

    // ---- block reduction -> private slot (plain stores, no atomics) ----
    if (lane == 0) { bsum[wave] = lsum; bcnt[wave] = hc; }
    __syncthreads();
    if (threadIdx.x == 0) {
        psum[blockIdx.x] = bsum[0] + bsum[1] + bsum[2] + bsum[3];
        pcnt[blockIdx.x] = bcnt[0] + bcnt[1] + bcnt[2] + bcnt[3];
    }
}

// Kernel 2: reduce the 2048 block partials. One block.
__global__ __launch_bounds__(256) void finalize_kernel(const float* __restrict__ psum,
                                                       const unsigned int* __restrict__ pcnt,
                                                       float* __restrict__ out) {
    float s = 0.0f;
    float c = 0.0f;                                      // hits < 2^24, exact in f32
    for (int t = threadIdx.x; t < NBLK; t += 256) {
        s += psum[t];
        c += (float)pcnt[t];
    }
#pragma unroll
    for (int off = 32; off >= 1; off >>= 1) {
        s += __shfl_xor(s, off, 64);
        c += __shfl_xor(c, off, 64);
    }
    __shared__ float ss[4], cc[4];
    const int wave = threadIdx.x >> 6;
    const int lane = threadIdx.x & 63;
    if (lane == 0) { ss[wave] = s; cc[wave] = c; }
    __syncthreads();
    if (threadIdx.x == 0) {
        const float S = ss[0] + ss[1] + ss[2] + ss[3];
        const float C = cc[0] + cc[1] + cc[2] + cc[3];
        out[0] = S / fmaxf(C, 1.0f);                     // max(cnt, 1)
    }
}

extern "C" void kernel_launch(void* const* d_in, const int* in_sizes, int n_in,
                              void* d_out, int out_size, void* d_ws, size_t ws_size,
                              hipStream_t stream) {
    const float* feat    = (const float*)d_in[0];   // [B,N,D] f32
    const float* pts_src = (const float*)d_in[1];   // [B,N,2] f32
    const float* pts_dst = (const float*)d_in[2];   // [B,B,N,2] f32
    // d_in[3] = invis_idx — unused by the reference
    const int* hptr = (const int*)d_in[4];          // height (scalar)
    const int* wptr = (const int*)d_in[5];          // width  (scalar)
    float* out = (float*)d_out;

    float*        psum  = (float*)d_ws;                          // 8 KB
    unsigned int* pcnt  = (unsigned int*)((char*)d_ws + 8192);   // 8 KB

    scan_kernel<<<NBLK, 256, 0, stream>>>(feat, pts_src, pts_dst,
                                          hptr, wptr, psum, pcnt);
    finalize_kernel<<<1, 256, 0, stream>>>(psum, pcnt, out);
}